// Round 10
// baseline (137.200 us; speedup 1.0000x reference)
//
#include <hip/hip_runtime.h>
#include <stdint.h>

#define NROWS 8192
#define KDIM  512                           // k elems (= bytes in fp8) per row
#define BM    256                           // 256x256 tiles
#define BK    64                            // k-bytes per MFMA stage
#define NKI   (KDIM / BK)                   // 8 K-iters
#define NT    (NROWS / BM)                  // 32 tiles per dim
#define NBLK  (NT * (NT + 1) / 2)           // 528 upper-tri blocks

typedef __attribute__((ext_vector_type(8)))  int   i32x8;
typedef __attribute__((ext_vector_type(16))) float f32x16;

// Kernel 1: row-normalize fp32 -> fp8 e4m3 (RNE), one wave per row.
// R20: NATURAL layout (swizzle dropped -- sim no longer stages through LDS,
// so there is no bank-conflict constraint; fragments are read directly from
// L2 in row-major order). Lane l holds elements [8l, 8l+8) of its row ->
// bytes [8l, 8l+8) of the fp8 row: one uint2 store at index row*64 + l.
__global__ __launch_bounds__(256) void prep_kernel(
    const float* __restrict__ src, unsigned char* __restrict__ dst,
    float* __restrict__ acc) {
  const int row  = blockIdx.x * 4 + (threadIdx.x >> 6);
  const int lane = threadIdx.x & 63;
  const float4 v0 = ((const float4*)src)[row * 128 + lane * 2];
  const float4 v1 = ((const float4*)src)[row * 128 + lane * 2 + 1];
  float ss = v0.x * v0.x + v0.y * v0.y + v0.z * v0.z + v0.w * v0.w
           + v1.x * v1.x + v1.y * v1.y + v1.z * v1.z + v1.w * v1.w;
  #pragma unroll
  for (int off = 32; off > 0; off >>= 1) ss += __shfl_down(ss, off);
  const float rn = 1.0f / sqrtf(__shfl(ss, 0));   // norms ~22.6, EPS never fires
  if (row == 0 && lane == 0) { acc[0] = 0.0f; ((unsigned int*)acc)[1] = 0u; }
  int pk0 = __builtin_amdgcn_cvt_pk_fp8_f32(v0.x * rn, v0.y * rn, 0, false);
  pk0     = __builtin_amdgcn_cvt_pk_fp8_f32(v0.z * rn, v0.w * rn, pk0, true);
  int pk1 = __builtin_amdgcn_cvt_pk_fp8_f32(v1.x * rn, v1.y * rn, 0, false);
  pk1     = __builtin_amdgcn_cvt_pk_fp8_f32(v1.z * rn, v1.w * rn, pk1, true);
  uint2 o; o.x = (unsigned int)pk0; o.y = (unsigned int)pk1;
  ((uint2*)dst)[row * 64 + lane] = o;               // natural order
}

__device__ __forceinline__ int tri_base(int b) {   // # tiles before row b
  return b * NT - (b * (b - 1)) / 2;
}

// Kernel 2: fp8 MX-MFMA GEMM (idn @ idn^T) fused with clamp, diag mask,
// reduction, finalize.
// R20 -- DIRECT L2->REGISTER, ZERO LDS, ZERO BARRIERS.
// Evidence: R12-R19 varied MFMA rate / traffic / makespan / barrier count /
// buffer depth / waves-per-SIMD around the stage->barrier->compute template;
// ALL null at sim ~ 33us = 27% of the ~9us MFMA roofline -- exactly m233's
// 2-phase plateau ("the ~72% gap is stage+vmcnt+barrier; removing single
// pieces doesn't help"). The template itself is the ceiling.
// This problem is special: the whole operand matrix is 4 MB = L2-resident
// on every XCD. LDS staging buys nothing (its only job is HBM-refetch
// avoidance). So fragments are loaded global->VGPR directly:
//   per wave, K-stage t: A-frag mi = i32x8 at row (bi*256+wrow+mi*32+r32),
//   bytes [t*64+h*32, +32) -- natural layout, 32B-aligned (2x dwordx4).
// Explicit 2-deep register pipeline (load t+1 || MFMA t), fully unrolled ->
// all frag-buffer indices static (rule #20: no scratch). No sync anywhere
// until the epilogue reduce. 2 waves/SIMD free-run and cover each other's
// ~200cyc L2 latency -- nothing ever re-syncs them.
// Cost: L2 read traffic 3x (per stage/block: A 4-way + B 2-way wave overlap
// = 96 KB vs 32 KB staged) = 405 MB total ~ 12us aggregate floor at
// 34.5 TB/s; A/B lines shared by co-resident waves hit L1 (32 KB).
// VGPR: acc 128 + frag dbuf 2x48 + addr/misc ~ 240 < 256 cap of
// __launch_bounds__(512,2). Spill signature if exceeded: sim WRITE_SIZE
// blowup (R14) -> fall back to single-buffered frags.
__global__ __launch_bounds__(512, 2) void sim_reduce_kernel(
    const unsigned char* __restrict__ idn, float* __restrict__ acc,
    float* __restrict__ out) {
  // triangular decode (block-uniform scalar math, R1-proven)
  const int idx = blockIdx.x;
  const float Af = 2.0f * NT + 1.0f;
  int bi = (int)((Af - sqrtf(Af * Af - 8.0f * (float)idx)) * 0.5f);
  while (bi > 0 && tri_base(bi) > idx) bi--;
  while (tri_base(bi + 1) <= idx) bi++;
  const int bj = bi + (idx - tri_base(bi));

  __shared__ float red[8];           // epilogue cross-wave reduce only

  const int tid  = threadIdx.x;      // 0..511, 8 waves
  const int lane = tid & 63;
  const int w    = tid >> 6;
  const int wrow = (w >> 2) * 128;   // wave's 128x64 output block (2x4 grid)
  const int wcol = (w & 3) * 64;
  const int r32  = lane & 31;        // row within 32-row MFMA tile
  const int h    = lane >> 5;        // k-half selector (k = h*32 + j)

  // per-lane fragment base addresses (natural layout)
  const unsigned char* ga = idn + (size_t)(bi * BM + wrow + r32) * KDIM + h * 32;
  const unsigned char* gb = idn + (size_t)(bj * BM + wcol + r32) * KDIM + h * 32;

  f32x16 acc_f[4][2];
  #pragma unroll
  for (int i = 0; i < 4; i++)
    #pragma unroll
    for (int j = 0; j < 2; j++)
      acc_f[i][j] = (f32x16){0.f, 0.f, 0.f, 0.f, 0.f, 0.f, 0.f, 0.f,
                             0.f, 0.f, 0.f, 0.f, 0.f, 0.f, 0.f, 0.f};

  i32x8 af[2][4], bf[2][2];          // 2-stage register pipeline

  // prologue: stage 0 fragments
  #pragma unroll
  for (int mi = 0; mi < 4; mi++)
    af[0][mi] = *(const i32x8*)(ga + (size_t)mi * 32 * KDIM);
  #pragma unroll
  for (int ni = 0; ni < 2; ni++)
    bf[0][ni] = *(const i32x8*)(gb + (size_t)ni * 32 * KDIM);

  #pragma unroll
  for (int t = 0; t < NKI; ++t) {    // fully unrolled: all t&1 fold static
    const int cs = t & 1;
    if (t + 1 < NKI) {               // issue stage t+1 loads (independent of
      const int ns = cs ^ 1;         //  stage-t MFMAs -> overlap, no barrier)
      const int ko = (t + 1) * BK;
      #pragma unroll
      for (int mi = 0; mi < 4; mi++)
        af[ns][mi] = *(const i32x8*)(ga + (size_t)mi * 32 * KDIM + ko);
      #pragma unroll
      for (int ni = 0; ni < 2; ni++)
        bf[ns][ni] = *(const i32x8*)(gb + (size_t)ni * 32 * KDIM + ko);
    }
    #pragma unroll
    for (int mi = 0; mi < 4; mi++)
      #pragma unroll
      for (int ni = 0; ni < 2; ni++)
        acc_f[mi][ni] = __builtin_amdgcn_mfma_scale_f32_32x32x64_f8f6f4(
            af[cs][mi], bf[cs][ni], acc_f[mi][ni],
            0, 0,                       // A fmt = fp8 e4m3, B fmt = fp8 e4m3
            0, 0x7F7F7F7Fu,             // A scale: E8M0 127 -> 1.0
            0, 0x7F7F7F7Fu);            // B scale: E8M0 127 -> 1.0
  }

  // Epilogue: clamp at zero, mask diagonal, reduce.
  // C/D layout for 32x32 shapes (m74/m101; dtype-independent m121-m128):
  // col = lane&31, row = (reg&3) + 8*(reg>>2) + 4*(lane>>5). R12-R19 verified.
  float local = 0.f;
  const bool diag = (bi == bj);
  #pragma unroll
  for (int mi = 0; mi < 4; mi++)
    #pragma unroll
    for (int ni = 0; ni < 2; ni++)
      #pragma unroll
      for (int rg = 0; rg < 16; rg++) {
        const int ri = wrow + mi * 32 + (rg & 3) + 8 * (rg >> 2) + 4 * h;
        const int ci = wcol + ni * 32 + r32;
        float v = fmaxf(acc_f[mi][ni][rg], 0.f);
        if (diag && ri == ci) v = 0.f;
        local += v;
      }

  #pragma unroll
  for (int off = 32; off > 0; off >>= 1) local += __shfl_down(local, off);
  if (lane == 0) red[w] = local;
  __syncthreads();                   // the only block-wide sync in the kernel
  if (tid == 0) {
    float s = red[0] + red[1] + red[2] + red[3]
            + red[4] + red[5] + red[6] + red[7];
    if (!diag) s *= 2.f;             // strictly-upper tiles cover both triangles
    atomicAdd(acc, s);
    // fused finalize: last-arriving block scales and writes both outputs.
    __threadfence();                               // acc-add visible before count
    unsigned int done = atomicAdd((unsigned int*)(acc + 1), 1u);
    if (done == NBLK - 1) {
      float total = atomicAdd(acc, 0.0f);          // device-scope RMW read
      const float m = total * (1.0f / ((float)NROWS * (float)NROWS));
      out[0] = m;
      out[1] = m;
    }
  }
}

extern "C" void kernel_launch(void* const* d_in, const int* in_sizes, int n_in,
                              void* d_out, int out_size, void* d_ws, size_t ws_size,
                              hipStream_t stream) {
  const float* id = (const float*)d_in[0];
  float* out = (float*)d_out;
  unsigned char* idn = (unsigned char*)d_ws;                       // 4 MB fp8
  float* acc = (float*)((char*)d_ws + (size_t)NROWS * KDIM);       // [0]=sum, [1]=counter

  prep_kernel<<<NROWS / 4, 256, 0, stream>>>(id, idn, acc);
  sim_reduce_kernel<<<NBLK, 512, 0, stream>>>(idn, acc, out);
}

// Round 11
// 98.644 us; speedup vs baseline: 1.3909x; 1.3909x over previous
//
#include <hip/hip_runtime.h>
#include <stdint.h>

#define NROWS 8192
#define KDIM  512                           // k elems (= bytes in fp8) per row
#define BM    256                           // 256x256 tiles
#define BK    64                            // k-bytes per MFMA stage
#define NKI   (KDIM / BK)                   // 8 K-iters
#define NT    (NROWS / BM)                  // 32 tiles per dim
#define NBLK  (NT * (NT + 1) / 2)           // 528 upper-tri blocks

typedef __attribute__((ext_vector_type(8)))  int   i32x8;
typedef __attribute__((ext_vector_type(16))) float f32x16;

// ---------------------------------------------------------------------------
// R21 FRAGMENT-PACKED LAYOUT.
// R20 post-mortem: direct L2->reg was LATENCY-bound (MfmaUtil 8%, FETCH only
// 16 MB, no spill) because fragment loads were uncoalesced: lane l read 32 B
// at row-stride 512 B -> each wave dwordx4 = 64 scattered 16-B L2 requests.
// LDS staging's real job here was coalescing, not HBM avoidance.
// Fix: prep stores idn in MFMA-FRAGMENT ORDER. For row-block rb (32 rows)
// and k-stage t, the fragment is 2 KB contiguous:
//   byte ((rb*8 + t)*64 + lane)*32 .. +32  holds row (rb*32 + (lane&31)),
//   k-bytes [t*64 + (lane>>5)*32, +32)
// A wave's frag load = base + lane*32: ONE contiguous 2 KB transaction.
// Bijective: uint2 index max = ((255*8+7)*64+63)*4+3 = 8192*64-1. Checked.
// ---------------------------------------------------------------------------

// Kernel 1: row-normalize fp32 -> fp8 e4m3 (RNE), one wave per row, store
// fragment-packed. Prep lane l holds bytes [8l, 8l+8) of its row; those map
// to t = l>>3, h = (l>>2)&1, chunk c = l&3 (8-byte units within the 32-B
// half). dst uint2 index = ((rb*8 + t)*64 + h*32 + r32)*4 + c.
// Store pattern per wave: 16 segments of 32 B -- acceptable for 4 MB total.
__global__ __launch_bounds__(256) void prep_kernel(
    const float* __restrict__ src, unsigned char* __restrict__ dst,
    float* __restrict__ acc) {
  const int row  = blockIdx.x * 4 + (threadIdx.x >> 6);
  const int lane = threadIdx.x & 63;
  const float4 v0 = ((const float4*)src)[row * 128 + lane * 2];
  const float4 v1 = ((const float4*)src)[row * 128 + lane * 2 + 1];
  float ss = v0.x * v0.x + v0.y * v0.y + v0.z * v0.z + v0.w * v0.w
           + v1.x * v1.x + v1.y * v1.y + v1.z * v1.z + v1.w * v1.w;
  #pragma unroll
  for (int off = 32; off > 0; off >>= 1) ss += __shfl_down(ss, off);
  const float rn = 1.0f / sqrtf(__shfl(ss, 0));   // norms ~22.6, EPS never fires
  if (row == 0 && lane == 0) { acc[0] = 0.0f; ((unsigned int*)acc)[1] = 0u; }
  int pk0 = __builtin_amdgcn_cvt_pk_fp8_f32(v0.x * rn, v0.y * rn, 0, false);
  pk0     = __builtin_amdgcn_cvt_pk_fp8_f32(v0.z * rn, v0.w * rn, pk0, true);
  int pk1 = __builtin_amdgcn_cvt_pk_fp8_f32(v1.x * rn, v1.y * rn, 0, false);
  pk1     = __builtin_amdgcn_cvt_pk_fp8_f32(v1.z * rn, v1.w * rn, pk1, true);
  const int rb  = row >> 5;
  const int r32 = row & 31;
  const int t   = lane >> 3;                        // k-stage (0..7)
  const int h   = (lane >> 2) & 1;                  // k-half
  const int c   = lane & 3;                         // 8-B chunk in 32-B half
  uint2 o; o.x = (unsigned int)pk0; o.y = (unsigned int)pk1;
  ((uint2*)dst)[((rb * 8 + t) * 64 + h * 32 + r32) * 4 + c] = o;
}

__device__ __forceinline__ int tri_base(int b) {   // # tiles before row b
  return b * NT - (b * (b - 1)) / 2;
}

// Kernel 2: fp8 MX-MFMA GEMM (idn @ idn^T) fused with clamp, diag mask,
// reduction, finalize. R20 structure (zero LDS for operands, zero barriers
// in the K-loop, 2-deep register pipeline) + R21 fragment-packed loads:
// frag (blk, t) at idn + (blk*8 + t)*2048 + lane*32 -- coalesced 2 KB/wave.
// Per block-stage: 8 waves x 6 frags = 96 KB L2 reads; total 405 MB ~ 12 us
// aggregate at L2 34.5 TB/s; A-frags shared by the 4 waves of a wave-row
// (L1/L2 hits). MFMA floor ~9 us. 16 independent loads in flight per wave,
// 16 waves/CU free-running -- no convoy, no re-sync.
// VGPR: frag dbuf 96 + addr; acc 128 in AGPR (unified file). No spill at
// R20's identical budget (verified: WRITE_SIZE 33 KB).
__global__ __launch_bounds__(512, 2) void sim_reduce_kernel(
    const unsigned char* __restrict__ idn, float* __restrict__ acc,
    float* __restrict__ out) {
  // triangular decode (block-uniform scalar math, R1-proven)
  const int idx = blockIdx.x;
  const float Af = 2.0f * NT + 1.0f;
  int bi = (int)((Af - sqrtf(Af * Af - 8.0f * (float)idx)) * 0.5f);
  while (bi > 0 && tri_base(bi) > idx) bi--;
  while (tri_base(bi + 1) <= idx) bi++;
  const int bj = bi + (idx - tri_base(bi));

  __shared__ float red[8];           // epilogue cross-wave reduce only

  const int tid  = threadIdx.x;      // 0..511, 8 waves
  const int lane = tid & 63;
  const int w    = tid >> 6;
  const int wrow = (w >> 2) * 128;   // wave's 128x64 output block (2x4 grid)
  const int wcol = (w & 3) * 64;
  const int r32  = lane & 31;        // row within 32-row MFMA tile
  const int h    = lane >> 5;        // k-half selector

  // fragment base addresses: blk index * 8 stages * 2 KB + lane*32
  const unsigned char* ga =
      idn + (size_t)(bi * 8 + (w >> 2) * 4) * 8 * 2048 + lane * 32;
  const unsigned char* gb =
      idn + (size_t)(bj * 8 + (w & 3) * 2) * 8 * 2048 + lane * 32;

  f32x16 acc_f[4][2];
  #pragma unroll
  for (int i = 0; i < 4; i++)
    #pragma unroll
    for (int j = 0; j < 2; j++)
      acc_f[i][j] = (f32x16){0.f, 0.f, 0.f, 0.f, 0.f, 0.f, 0.f, 0.f,
                             0.f, 0.f, 0.f, 0.f, 0.f, 0.f, 0.f, 0.f};

  i32x8 af[2][4], bf[2][2];          // 2-stage register pipeline

  // prologue: stage 0 fragments (frag (blk+mi, 0) = +mi*16 KB)
  #pragma unroll
  for (int mi = 0; mi < 4; mi++)
    af[0][mi] = *(const i32x8*)(ga + (size_t)mi * 8 * 2048);
  #pragma unroll
  for (int ni = 0; ni < 2; ni++)
    bf[0][ni] = *(const i32x8*)(gb + (size_t)ni * 8 * 2048);

  #pragma unroll
  for (int t = 0; t < NKI; ++t) {    // fully unrolled: all t&1 fold static
    const int cs = t & 1;
    if (t + 1 < NKI) {               // issue stage t+1 loads (independent of
      const int ns = cs ^ 1;         //  stage-t MFMAs -> overlap, no barrier)
      const size_t ko = (size_t)(t + 1) * 2048;
      #pragma unroll
      for (int mi = 0; mi < 4; mi++)
        af[ns][mi] = *(const i32x8*)(ga + (size_t)mi * 8 * 2048 + ko);
      #pragma unroll
      for (int ni = 0; ni < 2; ni++)
        bf[ns][ni] = *(const i32x8*)(gb + (size_t)ni * 8 * 2048 + ko);
    }
    #pragma unroll
    for (int mi = 0; mi < 4; mi++)
      #pragma unroll
      for (int ni = 0; ni < 2; ni++)
        acc_f[mi][ni] = __builtin_amdgcn_mfma_scale_f32_32x32x64_f8f6f4(
            af[cs][mi], bf[cs][ni], acc_f[mi][ni],
            0, 0,                       // A fmt = fp8 e4m3, B fmt = fp8 e4m3
            0, 0x7F7F7F7Fu,             // A scale: E8M0 127 -> 1.0
            0, 0x7F7F7F7Fu);            // B scale: E8M0 127 -> 1.0
  }

  // Epilogue: clamp at zero, mask diagonal, reduce.
  // C/D layout for 32x32 shapes (m74/m101; dtype-independent m121-m128):
  // col = lane&31, row = (reg&3) + 8*(reg>>2) + 4*(lane>>5). R12-R20 verified.
  float local = 0.f;
  const bool diag = (bi == bj);
  #pragma unroll
  for (int mi = 0; mi < 4; mi++)
    #pragma unroll
    for (int ni = 0; ni < 2; ni++)
      #pragma unroll
      for (int rg = 0; rg < 16; rg++) {
        const int ri = wrow + mi * 32 + (rg & 3) + 8 * (rg >> 2) + 4 * h;
        const int ci = wcol + ni * 32 + r32;
        float v = fmaxf(acc_f[mi][ni][rg], 0.f);
        if (diag && ri == ci) v = 0.f;
        local += v;
      }

  #pragma unroll
  for (int off = 32; off > 0; off >>= 1) local += __shfl_down(local, off);
  if (lane == 0) red[w] = local;
  __syncthreads();                   // the only block-wide sync in the kernel
  if (tid == 0) {
    float s = red[0] + red[1] + red[2] + red[3]
            + red[4] + red[5] + red[6] + red[7];
    if (!diag) s *= 2.f;             // strictly-upper tiles cover both triangles
    atomicAdd(acc, s);
    // fused finalize: last-arriving block scales and writes both outputs.
    __threadfence();                               // acc-add visible before count
    unsigned int done = atomicAdd((unsigned int*)(acc + 1), 1u);
    if (done == NBLK - 1) {
      float total = atomicAdd(acc, 0.0f);          // device-scope RMW read
      const float m = total * (1.0f / ((float)NROWS * (float)NROWS));
      out[0] = m;
      out[1] = m;
    }
  }
}

extern "C" void kernel_launch(void* const* d_in, const int* in_sizes, int n_in,
                              void* d_out, int out_size, void* d_ws, size_t ws_size,
                              hipStream_t stream) {
  const float* id = (const float*)d_in[0];
  float* out = (float*)d_out;
  unsigned char* idn = (unsigned char*)d_ws;                       // 4 MB fp8
  float* acc = (float*)((char*)d_ws + (size_t)NROWS * KDIM);       // [0]=sum, [1]=counter

  prep_kernel<<<NROWS / 4, 256, 0, stream>>>(id, idn, acc);
  sim_reduce_kernel<<<NBLK, 512, 0, stream>>>(idn, acc, out);
}